// Round 3
// baseline (489.530 us; speedup 1.0000x reference)
//
#include <hip/hip_runtime.h>
#include <hip/hip_bf16.h>
#include <cstdint>

#define B_ 32
#define S_ 4096
#define H_ 512

typedef _Float16 f16x8 __attribute__((ext_vector_type(8)));
typedef _Float16 f16x4 __attribute__((ext_vector_type(4)));
typedef float    f32x4 __attribute__((ext_vector_type(4)));

__device__ __forceinline__ float tanh_fast(float x) {
    // tanh(x) = 1 - 2/(exp(2x)+1); robust at +/-inf of the exp
    float e = __expf(2.0f * x);
    return 1.0f - 2.0f / (e + 1.0f);
}

// ---------------- prep: q = query @ Wq^T  (fp32, tiny) ----------------
__global__ void prep_q(const float* __restrict__ query,
                       const float* __restrict__ Wq,
                       float* __restrict__ q_ws) {
    int b = blockIdx.x;
    int t = threadIdx.x;              // 256 threads
    __shared__ float qs[H_];
    qs[t]       = query[b * H_ + t];
    qs[t + 256] = query[b * H_ + t + 256];
    __syncthreads();
    for (int ii = 0; ii < 2; ++ii) {
        int i = t + ii * 256;
        const float4* wrow = (const float4*)(Wq + (size_t)i * H_);
        float acc = 0.f;
        #pragma unroll 8
        for (int h4 = 0; h4 < H_ / 4; ++h4) {
            float4 w = wrow[h4];
            acc += qs[h4*4+0]*w.x + qs[h4*4+1]*w.y + qs[h4*4+2]*w.z + qs[h4*4+3]*w.w;
        }
        q_ws[b * H_ + i] = acc;
    }
}

// ------- prep: Wk fp32 -> fp16, pre-swizzled per-K-step tile layout -------
// Layout: wk16[ks][i][chunk_swz]  where ks=0..15 (K-step of 32), i=0..511 (row),
// 4 chunks of 8 halfs per row; chunk_swz = chunk ^ ((i>>1)&3)  (matches LDS reads)
__global__ void prep_wk(const float* __restrict__ Wk, _Float16* __restrict__ wk16) {
    int tid = blockIdx.x * 256 + threadIdx.x;   // 0..32767, one 16B chunk each
    int c  = tid & 3;
    int i  = (tid >> 2) & 511;
    int ks = tid >> 11;
    const float* src = Wk + (size_t)i * H_ + ks * 32 + c * 8;
    float4 a = *(const float4*)(src);
    float4 d = *(const float4*)(src + 4);
    f16x8 p;
    p[0] = (_Float16)a.x; p[1] = (_Float16)a.y; p[2] = (_Float16)a.z; p[3] = (_Float16)a.w;
    p[4] = (_Float16)d.x; p[5] = (_Float16)d.y; p[6] = (_Float16)d.z; p[7] = (_Float16)d.w;
    int swz = c ^ ((i >> 1) & 3);
    *(f16x8*)(wk16 + (size_t)ks * 16384 + i * 32 + swz * 8) = p;
}

// ------------- main: scores[bs] = sum_i tanh(q[b,i] + (keys@Wk^T)[bs,i]) * v[i] -------------
// Block: 64 rows x 512 cols (full N), 4 waves, each wave 64x128 (4 mf x 8 nf frags of 16x16x32)
__global__ __launch_bounds__(256, 2) void scores_kernel(
        const float* __restrict__ keys, const _Float16* __restrict__ wk16,
        const float* __restrict__ q_ws, const float* __restrict__ v,
        float* __restrict__ scores) {
    __shared__ __align__(16) _Float16 As[64 * 32];    // 4 KB, swizzled
    __shared__ __align__(16) _Float16 Bs[512 * 32];   // 32 KB, pre-swizzled in ws
    __shared__ float srow[4][64];

    int t    = threadIdx.x;
    int lane = t & 63;
    int wid  = t >> 6;          // 0..3 -> column range wid*128
    int m0   = blockIdx.x * 64; // global row base (never crosses b: 4096%64==0)
    int b    = m0 >> 12;

    f32x4 acc[4][8] = {};

    for (int ks = 0; ks < 16; ++ks) {
        __syncthreads();   // previous iteration's frag reads complete
        // ---- stage A: keys tile 64x32 fp32 -> fp16 LDS (swizzled) ----
        #pragma unroll
        for (int r2 = 0; r2 < 2; ++r2) {
            int idx = t + r2 * 256;       // 0..511
            int row = idx >> 3, c4 = idx & 7;
            float4 kv = *(const float4*)(keys + (size_t)(m0 + row) * H_ + ks * 32 + c4 * 4);
            f16x4 h;
            h[0] = (_Float16)kv.x; h[1] = (_Float16)kv.y;
            h[2] = (_Float16)kv.z; h[3] = (_Float16)kv.w;
            int chunk = c4 >> 1;
            int swz = chunk ^ ((row >> 1) & 3);
            *(f16x4*)&As[row * 32 + swz * 8 + (c4 & 1) * 4] = h;
        }
        // ---- stage B: 32 KB fp16 from L2 (already swizzled), linear copy ----
        {
            const uint4* bsrc = (const uint4*)(wk16 + (size_t)ks * 16384);
            uint4* bdst = (uint4*)Bs;
            #pragma unroll
            for (int j = 0; j < 8; ++j)
                bdst[t + j * 256] = bsrc[t + j * 256];
        }
        __syncthreads();
        // ---- fragments + MFMA ----
        int chunk = lane >> 4;
        f16x8 af[4];
        #pragma unroll
        for (int mf = 0; mf < 4; ++mf) {
            int row = mf * 16 + (lane & 15);
            af[mf] = *(const f16x8*)&As[row * 32 + (chunk ^ ((row >> 1) & 3)) * 8];
        }
        f16x8 bf[8];
        #pragma unroll
        for (int nf = 0; nf < 8; ++nf) {
            int row = wid * 128 + nf * 16 + (lane & 15);
            bf[nf] = *(const f16x8*)&Bs[row * 32 + (chunk ^ ((row >> 1) & 3)) * 8];
        }
        #pragma unroll
        for (int mf = 0; mf < 4; ++mf)
            #pragma unroll
            for (int nf = 0; nf < 8; ++nf)
                acc[mf][nf] = __builtin_amdgcn_mfma_f32_16x16x32_f16(af[mf], bf[nf], acc[mf][nf], 0, 0, 0);
    }

    // ---- epilogue: rowsum of tanh(q + k) * v ----
    float qv[8], vv[8];
    #pragma unroll
    for (int nf = 0; nf < 8; ++nf) {
        int col = wid * 128 + nf * 16 + (lane & 15);
        qv[nf] = q_ws[b * H_ + col];
        vv[nf] = v[col];
    }
    #pragma unroll
    for (int mf = 0; mf < 4; ++mf) {
        f32x4 rs = {0.f, 0.f, 0.f, 0.f};
        #pragma unroll
        for (int nf = 0; nf < 8; ++nf)
            #pragma unroll
            for (int r = 0; r < 4; ++r)
                rs[r] += tanh_fast(qv[nf] + acc[mf][nf][r]) * vv[nf];
        #pragma unroll
        for (int off = 1; off < 16; off <<= 1)
            #pragma unroll
            for (int r = 0; r < 4; ++r)
                rs[r] += __shfl_xor(rs[r], off);
        if ((lane & 15) == 0) {
            #pragma unroll
            for (int r = 0; r < 4; ++r)
                srow[wid][mf * 16 + (lane >> 4) * 4 + r] = rs[r];
        }
    }
    __syncthreads();
    if (t < 64)
        scores[m0 + t] = srow[0][t] + srow[1][t] + srow[2][t] + srow[3][t];
}

// ---------------- softmax over S with mask (mask is int32: bool -> const int*) ----------------
__global__ void softmax_kernel(const float* __restrict__ scores,
                               const int* __restrict__ mask,
                               float* __restrict__ attn) {
    int b = blockIdx.x, t = threadIdx.x;   // 256 threads
    __shared__ float red[8];
    float x[16];
    float m = -1e30f;
    #pragma unroll
    for (int j = 0; j < 16; ++j) {
        int s = t + j * 256;
        float sc = scores[b * S_ + s];
        x[j] = (mask[b * S_ + s] != 0) ? sc : -1e9f;
        m = fmaxf(m, x[j]);
    }
    #pragma unroll
    for (int off = 1; off < 64; off <<= 1) m = fmaxf(m, __shfl_xor(m, off));
    if ((t & 63) == 0) red[t >> 6] = m;
    __syncthreads();
    m = fmaxf(fmaxf(red[0], red[1]), fmaxf(red[2], red[3]));
    float sum = 0.f;
    #pragma unroll
    for (int j = 0; j < 16; ++j) { x[j] = __expf(x[j] - m); sum += x[j]; }
    #pragma unroll
    for (int off = 1; off < 64; off <<= 1) sum += __shfl_xor(sum, off);
    if ((t & 63) == 0) red[4 + (t >> 6)] = sum;
    __syncthreads();
    float inv = 1.0f / (red[4] + red[5] + red[6] + red[7]);
    #pragma unroll
    for (int j = 0; j < 16; ++j)
        attn[b * S_ + t + j * 256] = x[j] * inv;
}

// ---------------- ctx = attn @ keys  (memory-bound) ----------------
__global__ void ctx_kernel(const float* __restrict__ keys,
                           const float* __restrict__ attn,
                           float* __restrict__ ctx) {
    int blk = blockIdx.x;
    int b = blk >> 4, c = blk & 15;
    int s0 = c * 256;
    int t = threadIdx.x;   // 256
    __shared__ float attn_s[256];
    __shared__ float ctx_l[512];
    attn_s[t] = attn[b * S_ + s0 + t];
    __syncthreads();
    int h4 = t & 127, sp = t >> 7;
    f32x4 acc = {0.f, 0.f, 0.f, 0.f};
    const float4* kb = (const float4*)(keys + ((size_t)b * S_ + s0) * H_);
    for (int it = 0; it < 128; ++it) {
        int srow = it * 2 + sp;
        float a = attn_s[srow];
        float4 kv = kb[(size_t)srow * 128 + h4];
        acc[0] += a * kv.x; acc[1] += a * kv.y; acc[2] += a * kv.z; acc[3] += a * kv.w;
    }
    if (sp == 0) {
        #pragma unroll
        for (int r = 0; r < 4; ++r) ctx_l[h4 * 4 + r] = acc[r];
    }
    __syncthreads();
    if (sp == 1) {
        #pragma unroll
        for (int r = 0; r < 4; ++r) ctx_l[h4 * 4 + r] += acc[r];
    }
    __syncthreads();
    atomicAdd(&ctx[b * H_ + t], ctx_l[t]);
    atomicAdd(&ctx[b * H_ + t + 256], ctx_l[t + 256]);
}

extern "C" void kernel_launch(void* const* d_in, const int* in_sizes, int n_in,
                              void* d_out, int out_size, void* d_ws, size_t ws_size,
                              hipStream_t stream) {
    const float* query = (const float*)d_in[0];
    const float* keys  = (const float*)d_in[1];
    const int*   mask  = (const int*)d_in[2];   // jnp bool uploads as int32 per harness
    const float* Wq    = (const float*)d_in[3];
    const float* Wk    = (const float*)d_in[4];
    const float* v     = (const float*)d_in[5];

    float* out  = (float*)d_out;
    float* ctx  = out;             // [32*512]
    float* attn = out + B_ * H_;   // [32*4096]

    char* ws = (char*)d_ws;
    float*    q_ws   = (float*)ws;                          // 64 KB
    _Float16* wk16   = (_Float16*)(ws + 65536);             // 512 KB
    float*    scores = (float*)(ws + 65536 + 524288);       // 512 KB

    hipMemsetAsync(ctx, 0, B_ * H_ * sizeof(float), stream);
    prep_q<<<32, 256, 0, stream>>>(query, Wq, q_ws);
    prep_wk<<<128, 256, 0, stream>>>(Wk, wk16);
    scores_kernel<<<2048, 256, 0, stream>>>(keys, wk16, q_ws, v, scores);
    softmax_kernel<<<32, 256, 0, stream>>>(scores, mask, attn);
    ctx_kernel<<<512, 256, 0, stream>>>(keys, attn, ctx);
}